// Round 3
// baseline (543.246 us; speedup 1.0000x reference)
//
#include <hip/hip_runtime.h>
#include <hip/hip_bf16.h>

#define N_NODES 8192
#define F_IN    128
#define F_OUT   64
#define GAT_ALPHA 0.2f
#define JSPLIT  16
#define COLS_PER_SPLIT (N_NODES / JSPLIT)   // 512
#define KC      64                           // columns per chunk
#define NCH     (COLS_PER_SPLIT / KC)        // 8
#define LSTR    72                           // padded LDS stride (bf16 elems, 144B rows)

typedef short  short8_t  __attribute__((ext_vector_type(8)));
typedef float  f32x4_t   __attribute__((ext_vector_type(4)));

static __device__ __forceinline__ unsigned int f32_to_bf16_bits(float x) {
    unsigned int u = __float_as_uint(x);
    return (u + 0x7fffu + ((u >> 16) & 1u)) >> 16;
}

// Kernel 1: Wh = h @ W (fp32); s1 = Wh@a1, s2 = Wh@a2.
// Wh stored bf16 in LOAD-ORDER tiles: wht[node/64][instr 0..7][lane 0..63][elem 0..7]
//   node c (in tile): kk=c>>5, q=(c>>3)&3, e=c&7;  feature f: t=f>>4, m=f&15
//   -> instr = kk*4+t, lane = q*16+m, elem = e.
__global__ __launch_bounds__(256) void k_wh(
    const float* __restrict__ h, const float* __restrict__ W, const float* __restrict__ a,
    unsigned short* __restrict__ wht, float* __restrict__ s1, float* __restrict__ s2)
{
    __shared__ float Wl[F_IN][F_OUT];   // 32 KB
    int tid = threadIdx.x;
    #pragma unroll
    for (int i = 0; i < (F_IN * F_OUT) / 256; ++i) {
        int idx = tid + i * 256;
        Wl[idx >> 6][idx & 63] = W[idx];
    }
    __syncthreads();
    int wave = tid >> 6, lane = tid & 63;
    int row = blockIdx.x * 4 + wave;
    const float* hr = h + (size_t)row * F_IN;
    float acc = 0.f;
    #pragma unroll
    for (int k = 0; k < F_IN; k += 4) {
        float4 hv = *(const float4*)(hr + k);
        acc += hv.x * Wl[k + 0][lane];
        acc += hv.y * Wl[k + 1][lane];
        acc += hv.z * Wl[k + 2][lane];
        acc += hv.w * Wl[k + 3][lane];
    }
    int c  = row & 63, cb = row >> 6;
    int u  = ((c >> 5) << 2) + (lane >> 4);          // kk*4 + t
    int lp = (((c >> 3) & 3) << 4) + (lane & 15);    // q*16 + m
    wht[(size_t)cb * 4096 + u * 512 + lp * 8 + (c & 7)] =
        (unsigned short)f32_to_bf16_bits(acc);

    float p1 = acc * a[lane];
    float p2 = acc * a[F_OUT + lane];
    #pragma unroll
    for (int off = 32; off > 0; off >>= 1) {
        p1 += __shfl_down(p1, off);
        p2 += __shfl_down(p2, off);
    }
    if (lane == 0) { s1[row] = p1; s2[row] = p2; }
}

// Stream register set: one chunk of adj/ef/s2 (36 VGPRs).
struct SSet {
    int4   aj0, aj1, aj2, aj3;
    float4 ev0, ev1, ev2, ev3;
    float4 sv;
};

#define RSTR ((size_t)4 * N_NODES)

static __device__ __forceinline__ void load_streams(
    SSet& S, const int* adjp, const float* efp, const float* s2p)
{
    S.aj0 = *(const int4*)  (adjp + 0 * RSTR);
    S.aj1 = *(const int4*)  (adjp + 1 * RSTR);
    S.aj2 = *(const int4*)  (adjp + 2 * RSTR);
    S.aj3 = *(const int4*)  (adjp + 3 * RSTR);
    S.ev0 = *(const float4*)(efp  + 0 * RSTR);
    S.ev1 = *(const float4*)(efp  + 1 * RSTR);
    S.ev2 = *(const float4*)(efp  + 2 * RSTR);
    S.ev3 = *(const float4*)(efp  + 3 * RSTR);
    S.sv  = *(const float4*)s2p;
}

static __device__ __forceinline__ uint2 make_pk(
    int4 aj, float4 ev, float sb, float4 sv, float a_e)
{
    float e0 = fmaf(ev.x, a_e, sb + sv.x); e0 = fmaxf(e0, GAT_ALPHA * e0);
    float e1 = fmaf(ev.y, a_e, sb + sv.y); e1 = fmaxf(e1, GAT_ALPHA * e1);
    float e2 = fmaf(ev.z, a_e, sb + sv.z); e2 = fmaxf(e2, GAT_ALPHA * e2);
    float e3 = fmaf(ev.w, a_e, sb + sv.w); e3 = fmaxf(e3, GAT_ALPHA * e3);
    float p0 = (aj.x > 0) ? __expf(e0) : 0.f;
    float p1 = (aj.y > 0) ? __expf(e1) : 0.f;
    float p2 = (aj.z > 0) ? __expf(e2) : 0.f;
    float p3 = (aj.w > 0) ? __expf(e3) : 0.f;
    uint2 r;
    r.x = f32_to_bf16_bits(p0) | (f32_to_bf16_bits(p1) << 16);
    r.y = f32_to_bf16_bits(p2) | (f32_to_bf16_bits(p3) << 16);
    return r;
}

// Kernel 2: per-wave-independent, 2-deep software pipeline, no __syncthreads.
// Wave: 16 rows x 512 cols. Ping-pong stream sets S0/S1: chunk ch+2's streams are
// issued right after chunk ch's are consumed -> ~2 chunk-times of HBM-latency
// coverage. __launch_bounds__(256,2) lifts the VGPR cap so the whole live set
// (S0+S1+b-frags+acc) stays in registers (the round-1 80-VGPR squeeze collapsed
// the pipeline to one exposed HBM latency per chunk).
__global__ __launch_bounds__(256, 2) void k_attn(
    const int* __restrict__ adj, const float* __restrict__ ef,
    const float* __restrict__ a,
    const float* __restrict__ s1, const float* __restrict__ s2,
    const unsigned short* __restrict__ wht,
    float* __restrict__ Osum, float* __restrict__ lsum)
{
    __shared__ unsigned short pl[4 * 2 * 16 * LSTR];   // 18432 B
    int tid  = threadIdx.x;
    int wave = tid >> 6, lane = tid & 63;
    int q = lane >> 4, m = lane & 15;   // MFMA-read roles
    int rg = q, sg = m;                 // load roles (same lane decomposition)
    int rowtile = blockIdx.x / JSPLIT;
    int split   = blockIdx.x % JSPLIT;
    int row0  = rowtile * 64 + wave * 16;
    int jbase = split * COLS_PER_SPLIT;

    float a_e = a[2 * F_OUT];
    float s1v0 = s1[row0 + 0 + rg];
    float s1v1 = s1[row0 + 4 + rg];
    float s1v2 = s1[row0 + 8 + rg];
    float s1v3 = s1[row0 + 12 + rg];

    const int*   adjp = adj + (size_t)(row0 + rg) * N_NODES + jbase + sg * 4;
    const float* efp  = ef  + (size_t)(row0 + rg) * N_NODES + jbase + sg * 4;
    const float* s2p  = s2 + jbase + sg * 4;
    const unsigned short* w3 = wht + (size_t)(split * NCH) * 4096 + lane * 8;
    unsigned short* plw = pl + wave * (2 * 16 * LSTR);

    f32x4_t acc0 = {0.f, 0.f, 0.f, 0.f};
    f32x4_t acc1 = acc0, acc2 = acc0, acc3 = acc0, accl = acc0;
    short8_t ones;
    #pragma unroll
    for (int i = 0; i < 8; ++i) ones[i] = (short)0x3F80;   // bf16 1.0

    // prologue: 2-deep prefetch (chunks 0 and 1; 72 VGPRs of stream data in flight)
    SSet S0, S1;
    load_streams(S0, adjp, efp, s2p);
    load_streams(S1, adjp + KC, efp + KC, s2p + KC);
    adjp += 2 * KC; efp += 2 * KC; s2p += 2 * KC;   // now at chunk 2

    // one chunk iteration: consume S (chunk ch), optionally prefetch chunk ch+2 into S
    auto iter = [&](int ch, SSet& S, bool pf) {
        // 1) B-fragment loads for this chunk: 8 contiguous 1KB wave reads (L2-hot)
        const unsigned short* wt = w3 + (size_t)ch * 4096;
        short8_t b0 = *(const short8_t*)(wt + 0 * 512);
        short8_t b1 = *(const short8_t*)(wt + 1 * 512);
        short8_t b2 = *(const short8_t*)(wt + 2 * 512);
        short8_t b3 = *(const short8_t*)(wt + 3 * 512);
        short8_t b4 = *(const short8_t*)(wt + 4 * 512);
        short8_t b5 = *(const short8_t*)(wt + 5 * 512);
        short8_t b6 = *(const short8_t*)(wt + 6 * 512);
        short8_t b7 = *(const short8_t*)(wt + 7 * 512);

        // 2) compute p from prefetched registers (frees S)
        uint2 pk0 = make_pk(S.aj0, S.ev0, s1v0, S.sv, a_e);
        uint2 pk1 = make_pk(S.aj1, S.ev1, s1v1, S.sv, a_e);
        uint2 pk2 = make_pk(S.aj2, S.ev2, s1v2, S.sv, a_e);
        uint2 pk3 = make_pk(S.aj3, S.ev3, s1v3, S.sv, a_e);

        // 3) prefetch chunk ch+2 into S — issued ~2 iterations before use
        if (pf) {
            load_streams(S, adjp, efp, s2p);
            adjp += KC; efp += KC; s2p += KC;
        }

        // 4) p-tile to wave-private LDS (double-buffered; wave-local => no barrier)
        unsigned short* pb = plw + (ch & 1) * (16 * LSTR);
        *(uint2*)&pb[(0 * 4 + rg) * LSTR + sg * 4] = pk0;
        *(uint2*)&pb[(1 * 4 + rg) * LSTR + sg * 4] = pk1;
        *(uint2*)&pb[(2 * 4 + rg) * LSTR + sg * 4] = pk2;
        *(uint2*)&pb[(3 * 4 + rg) * LSTR + sg * 4] = pk3;

        // 5) MFMA phase: A-frags from LDS, consume B-loads
        const unsigned short* pr = pb + m * LSTR;
        {
            short8_t af = *(const short8_t*)&pr[0 * 32 + q * 8];
            acc0 = __builtin_amdgcn_mfma_f32_16x16x32_bf16(af, b0, acc0, 0, 0, 0);
            acc1 = __builtin_amdgcn_mfma_f32_16x16x32_bf16(af, b1, acc1, 0, 0, 0);
            acc2 = __builtin_amdgcn_mfma_f32_16x16x32_bf16(af, b2, acc2, 0, 0, 0);
            acc3 = __builtin_amdgcn_mfma_f32_16x16x32_bf16(af, b3, acc3, 0, 0, 0);
            accl = __builtin_amdgcn_mfma_f32_16x16x32_bf16(af, ones, accl, 0, 0, 0);
        }
        {
            short8_t af = *(const short8_t*)&pr[1 * 32 + q * 8];
            acc0 = __builtin_amdgcn_mfma_f32_16x16x32_bf16(af, b4, acc0, 0, 0, 0);
            acc1 = __builtin_amdgcn_mfma_f32_16x16x32_bf16(af, b5, acc1, 0, 0, 0);
            acc2 = __builtin_amdgcn_mfma_f32_16x16x32_bf16(af, b6, acc2, 0, 0, 0);
            acc3 = __builtin_amdgcn_mfma_f32_16x16x32_bf16(af, b7, acc3, 0, 0, 0);
            accl = __builtin_amdgcn_mfma_f32_16x16x32_bf16(af, ones, accl, 0, 0, 0);
        }
    };

    // NCH = 8, fully unrolled ping-pong schedule (all S indices compile-time)
    iter(0, S0, true);    // prefetch ch2
    iter(1, S1, true);    // prefetch ch3
    iter(2, S0, true);    // prefetch ch4
    iter(3, S1, true);    // prefetch ch5
    iter(4, S0, true);    // prefetch ch6
    iter(5, S1, true);    // prefetch ch7
    iter(6, S0, false);
    iter(7, S1, false);

    #pragma unroll
    for (int rr = 0; rr < 4; ++rr) {
        int orow = row0 + q * 4 + rr;
        float* op = Osum + (size_t)orow * F_OUT + m;
        atomicAdd(op +  0, acc0[rr]);
        atomicAdd(op + 16, acc1[rr]);
        atomicAdd(op + 32, acc2[rr]);
        atomicAdd(op + 48, acc3[rr]);
    }
    if (m == 0) {
        #pragma unroll
        for (int rr = 0; rr < 4; ++rr)
            atomicAdd(&lsum[row0 + q * 4 + rr], accl[rr]);
    }
}

// Kernel 3: normalize + ELU
__global__ __launch_bounds__(256) void k_out(
    const float* __restrict__ Osum, const float* __restrict__ lsum, float* __restrict__ out)
{
    int i = blockIdx.x * 256 + threadIdx.x;
    float v = Osum[i] / lsum[i >> 6];
    out[i] = (v > 0.f) ? v : (__expf(v) - 1.f);
}

extern "C" void kernel_launch(void* const* d_in, const int* in_sizes, int n_in,
                              void* d_out, int out_size, void* d_ws, size_t ws_size,
                              hipStream_t stream)
{
    const float* h   = (const float*)d_in[0];
    const int*   adj = (const int*)d_in[1];
    const float* ef  = (const float*)d_in[2];
    const float* W   = (const float*)d_in[3];
    const float* a   = (const float*)d_in[4];
    float* out = (float*)d_out;

    char* ws = (char*)d_ws;
    unsigned short* wht = (unsigned short*)ws;                       // 1 MB
    float* s1   = (float*)(ws + (size_t)F_OUT * N_NODES * 2);        // 32 KB
    float* s2   = s1 + N_NODES;                                      // 32 KB
    float* Osum = s2 + N_NODES;                                      // 2 MB
    float* lsum = Osum + (size_t)N_NODES * F_OUT;                    // 32 KB

    hipMemsetAsync(Osum, 0, ((size_t)N_NODES * F_OUT + N_NODES) * sizeof(float), stream);

    k_wh  <<<N_NODES / 4, 256, 0, stream>>>(h, W, a, wht, s1, s2);
    k_attn<<<(N_NODES / 64) * JSPLIT, 256, 0, stream>>>(adj, ef, a, s1, s2, wht, Osum, lsum);
    k_out <<<(N_NODES * F_OUT) / 256, 256, 0, stream>>>(Osum, lsum, out);
}

// Round 4
// 531.747 us; speedup vs baseline: 1.0216x; 1.0216x over previous
//
#include <hip/hip_runtime.h>
#include <hip/hip_bf16.h>

#define N_NODES 8192
#define F_IN    128
#define F_OUT   64
#define GAT_ALPHA 0.2f
#define JSPLIT  16
#define COLS_PER_SPLIT (N_NODES / JSPLIT)   // 512
#define KC      64                           // columns per chunk
#define NCH     (COLS_PER_SPLIT / KC)        // 8
#define LSTR    72                           // padded LDS stride (bf16 elems, 144B rows)

typedef short  short8_t  __attribute__((ext_vector_type(8)));
typedef float  f32x4_t   __attribute__((ext_vector_type(4)));

static __device__ __forceinline__ unsigned int f32_to_bf16_bits(float x) {
    unsigned int u = __float_as_uint(x);
    return (u + 0x7fffu + ((u >> 16) & 1u)) >> 16;
}

// Kernel 1: Wh = h @ W (fp32); s1 = Wh@a1, s2 = Wh@a2.
// Wh stored bf16 in LOAD-ORDER tiles: wht[node/64][instr 0..7][lane 0..63][elem 0..7]
//   node c (in tile): kk=c>>5, q=(c>>3)&3, e=c&7;  feature f: t=f>>4, m=f&15
//   -> instr = kk*4+t, lane = q*16+m, elem = e.
__global__ __launch_bounds__(256) void k_wh(
    const float* __restrict__ h, const float* __restrict__ W, const float* __restrict__ a,
    unsigned short* __restrict__ wht, float* __restrict__ s1, float* __restrict__ s2)
{
    __shared__ float Wl[F_IN][F_OUT];   // 32 KB
    int tid = threadIdx.x;
    #pragma unroll
    for (int i = 0; i < (F_IN * F_OUT) / 256; ++i) {
        int idx = tid + i * 256;
        Wl[idx >> 6][idx & 63] = W[idx];
    }
    __syncthreads();
    int wave = tid >> 6, lane = tid & 63;
    int row = blockIdx.x * 4 + wave;
    const float* hr = h + (size_t)row * F_IN;
    float acc = 0.f;
    #pragma unroll
    for (int k = 0; k < F_IN; k += 4) {
        float4 hv = *(const float4*)(hr + k);
        acc += hv.x * Wl[k + 0][lane];
        acc += hv.y * Wl[k + 1][lane];
        acc += hv.z * Wl[k + 2][lane];
        acc += hv.w * Wl[k + 3][lane];
    }
    int c  = row & 63, cb = row >> 6;
    int u  = ((c >> 5) << 2) + (lane >> 4);          // kk*4 + t
    int lp = (((c >> 3) & 3) << 4) + (lane & 15);    // q*16 + m
    wht[(size_t)cb * 4096 + u * 512 + lp * 8 + (c & 7)] =
        (unsigned short)f32_to_bf16_bits(acc);

    float p1 = acc * a[lane];
    float p2 = acc * a[F_OUT + lane];
    #pragma unroll
    for (int off = 32; off > 0; off >>= 1) {
        p1 += __shfl_down(p1, off);
        p2 += __shfl_down(p2, off);
    }
    if (lane == 0) { s1[row] = p1; s2[row] = p2; }
}

// Stream register set: one chunk of adj/ef/s2 (36 VGPRs).
struct SSet {
    int4   aj0, aj1, aj2, aj3;
    float4 ev0, ev1, ev2, ev3;
    float4 sv;
};

#define RSTR ((size_t)4 * N_NODES)

static __device__ __forceinline__ void load_streams(
    SSet& S, const int* adjp, const float* efp, const float* s2p)
{
    S.aj0 = *(const int4*)  (adjp + 0 * RSTR);
    S.aj1 = *(const int4*)  (adjp + 1 * RSTR);
    S.aj2 = *(const int4*)  (adjp + 2 * RSTR);
    S.aj3 = *(const int4*)  (adjp + 3 * RSTR);
    S.ev0 = *(const float4*)(efp  + 0 * RSTR);
    S.ev1 = *(const float4*)(efp  + 1 * RSTR);
    S.ev2 = *(const float4*)(efp  + 2 * RSTR);
    S.ev3 = *(const float4*)(efp  + 3 * RSTR);
    S.sv  = *(const float4*)s2p;
}

static __device__ __forceinline__ uint2 make_pk(
    int4 aj, float4 ev, float sb, float4 sv, float a_e)
{
    float e0 = fmaf(ev.x, a_e, sb + sv.x); e0 = fmaxf(e0, GAT_ALPHA * e0);
    float e1 = fmaf(ev.y, a_e, sb + sv.y); e1 = fmaxf(e1, GAT_ALPHA * e1);
    float e2 = fmaf(ev.z, a_e, sb + sv.z); e2 = fmaxf(e2, GAT_ALPHA * e2);
    float e3 = fmaf(ev.w, a_e, sb + sv.w); e3 = fmaxf(e3, GAT_ALPHA * e3);
    float p0 = (aj.x > 0) ? __expf(e0) : 0.f;
    float p1 = (aj.y > 0) ? __expf(e1) : 0.f;
    float p2 = (aj.z > 0) ? __expf(e2) : 0.f;
    float p3 = (aj.w > 0) ? __expf(e3) : 0.f;
    uint2 r;
    r.x = f32_to_bf16_bits(p0) | (f32_to_bf16_bits(p1) << 16);
    r.y = f32_to_bf16_bits(p2) | (f32_to_bf16_bits(p3) << 16);
    return r;
}

// Kernel 2: per-wave-independent, pipeline PINNED with sched_barrier(0).
// Per chunk, two scheduler regions the compiler cannot mix:
//  region A: b-frag loads (L2-hot, 8) then next-chunk stream prefetch (HBM, 9).
//            vmcnt issue order: S_cur (oldest) < b < S_next (youngest).
//  region B: p-compute from S_cur (auto-wait vmcnt(17): leaves b+S_next in
//            flight), LDS p-tile, MFMA (auto-wait vmcnt(9): leaves S_next in
//            flight across the iteration boundary).
// This forces the allocator to keep S_next live (~150 VGPR) instead of the
// round-3 behavior (VGPR=64: every prefetch sunk to its use = serial chains).
__global__ __launch_bounds__(256, 2) void k_attn(
    const int* __restrict__ adj, const float* __restrict__ ef,
    const float* __restrict__ a,
    const float* __restrict__ s1, const float* __restrict__ s2,
    const unsigned short* __restrict__ wht,
    float* __restrict__ Osum, float* __restrict__ lsum)
{
    __shared__ unsigned short pl[4 * 2 * 16 * LSTR];   // 18432 B
    int tid  = threadIdx.x;
    int wave = tid >> 6, lane = tid & 63;
    int q = lane >> 4, m = lane & 15;   // MFMA-read roles
    int rg = q, sg = m;                 // load roles (same lane decomposition)
    int rowtile = blockIdx.x / JSPLIT;
    int split   = blockIdx.x % JSPLIT;
    int row0  = rowtile * 64 + wave * 16;
    int jbase = split * COLS_PER_SPLIT;

    float a_e = a[2 * F_OUT];
    float s1v0 = s1[row0 + 0 + rg];
    float s1v1 = s1[row0 + 4 + rg];
    float s1v2 = s1[row0 + 8 + rg];
    float s1v3 = s1[row0 + 12 + rg];

    const int*   adjp = adj + (size_t)(row0 + rg) * N_NODES + jbase + sg * 4;
    const float* efp  = ef  + (size_t)(row0 + rg) * N_NODES + jbase + sg * 4;
    const float* s2p  = s2 + jbase + sg * 4;
    const unsigned short* w3 = wht + (size_t)(split * NCH) * 4096 + lane * 8;
    unsigned short* plw = pl + wave * (2 * 16 * LSTR);

    f32x4_t acc0 = {0.f, 0.f, 0.f, 0.f};
    f32x4_t acc1 = acc0, acc2 = acc0, acc3 = acc0, accl = acc0;
    short8_t ones;
    #pragma unroll
    for (int i = 0; i < 8; ++i) ones[i] = (short)0x3F80;   // bf16 1.0

    // prologue: load chunk 0 streams; pointers advance to chunk 1
    SSet S0, S1;
    load_streams(S0, adjp, efp, s2p);
    adjp += KC; efp += KC; s2p += KC;

    // one chunk iteration: consume Scur (chunk ch), prefetch chunk ch+1 into Snx
    auto iter = [&](int ch, SSet& Scur, SSet& Snx, bool pf) {
        // ---- region A: b-loads FIRST (older than prefetch), then prefetch ----
        const unsigned short* wt = w3 + (size_t)ch * 4096;
        short8_t b0 = *(const short8_t*)(wt + 0 * 512);
        short8_t b1 = *(const short8_t*)(wt + 1 * 512);
        short8_t b2 = *(const short8_t*)(wt + 2 * 512);
        short8_t b3 = *(const short8_t*)(wt + 3 * 512);
        short8_t b4 = *(const short8_t*)(wt + 4 * 512);
        short8_t b5 = *(const short8_t*)(wt + 5 * 512);
        short8_t b6 = *(const short8_t*)(wt + 6 * 512);
        short8_t b7 = *(const short8_t*)(wt + 7 * 512);

        if (pf) {
            load_streams(Snx, adjp, efp, s2p);
            adjp += KC; efp += KC; s2p += KC;
        }

        __builtin_amdgcn_sched_barrier(0);   // nothing crosses: prefetch cannot sink

        // ---- region B: consume Scur, LDS p-tile, MFMA ----
        uint2 pk0 = make_pk(Scur.aj0, Scur.ev0, s1v0, Scur.sv, a_e);
        uint2 pk1 = make_pk(Scur.aj1, Scur.ev1, s1v1, Scur.sv, a_e);
        uint2 pk2 = make_pk(Scur.aj2, Scur.ev2, s1v2, Scur.sv, a_e);
        uint2 pk3 = make_pk(Scur.aj3, Scur.ev3, s1v3, Scur.sv, a_e);

        unsigned short* pb = plw + (ch & 1) * (16 * LSTR);
        *(uint2*)&pb[(0 * 4 + rg) * LSTR + sg * 4] = pk0;
        *(uint2*)&pb[(1 * 4 + rg) * LSTR + sg * 4] = pk1;
        *(uint2*)&pb[(2 * 4 + rg) * LSTR + sg * 4] = pk2;
        *(uint2*)&pb[(3 * 4 + rg) * LSTR + sg * 4] = pk3;

        const unsigned short* pr = pb + m * LSTR;
        {
            short8_t af = *(const short8_t*)&pr[0 * 32 + q * 8];
            acc0 = __builtin_amdgcn_mfma_f32_16x16x32_bf16(af, b0, acc0, 0, 0, 0);
            acc1 = __builtin_amdgcn_mfma_f32_16x16x32_bf16(af, b1, acc1, 0, 0, 0);
            acc2 = __builtin_amdgcn_mfma_f32_16x16x32_bf16(af, b2, acc2, 0, 0, 0);
            acc3 = __builtin_amdgcn_mfma_f32_16x16x32_bf16(af, b3, acc3, 0, 0, 0);
            accl = __builtin_amdgcn_mfma_f32_16x16x32_bf16(af, ones, accl, 0, 0, 0);
        }
        {
            short8_t af = *(const short8_t*)&pr[1 * 32 + q * 8];
            acc0 = __builtin_amdgcn_mfma_f32_16x16x32_bf16(af, b4, acc0, 0, 0, 0);
            acc1 = __builtin_amdgcn_mfma_f32_16x16x32_bf16(af, b5, acc1, 0, 0, 0);
            acc2 = __builtin_amdgcn_mfma_f32_16x16x32_bf16(af, b6, acc2, 0, 0, 0);
            acc3 = __builtin_amdgcn_mfma_f32_16x16x32_bf16(af, b7, acc3, 0, 0, 0);
            accl = __builtin_amdgcn_mfma_f32_16x16x32_bf16(af, ones, accl, 0, 0, 0);
        }
    };

    // NCH = 8, fully unrolled; Scur/Snx alternate (all compile-time)
    iter(0, S0, S1, true);
    iter(1, S1, S0, true);
    iter(2, S0, S1, true);
    iter(3, S1, S0, true);
    iter(4, S0, S1, true);
    iter(5, S1, S0, true);
    iter(6, S0, S1, true);
    iter(7, S1, S0, false);

    #pragma unroll
    for (int rr = 0; rr < 4; ++rr) {
        int orow = row0 + q * 4 + rr;
        float* op = Osum + (size_t)orow * F_OUT + m;
        atomicAdd(op +  0, acc0[rr]);
        atomicAdd(op + 16, acc1[rr]);
        atomicAdd(op + 32, acc2[rr]);
        atomicAdd(op + 48, acc3[rr]);
    }
    if (m == 0) {
        #pragma unroll
        for (int rr = 0; rr < 4; ++rr)
            atomicAdd(&lsum[row0 + q * 4 + rr], accl[rr]);
    }
}

// Kernel 3: normalize + ELU
__global__ __launch_bounds__(256) void k_out(
    const float* __restrict__ Osum, const float* __restrict__ lsum, float* __restrict__ out)
{
    int i = blockIdx.x * 256 + threadIdx.x;
    float v = Osum[i] / lsum[i >> 6];
    out[i] = (v > 0.f) ? v : (__expf(v) - 1.f);
}

extern "C" void kernel_launch(void* const* d_in, const int* in_sizes, int n_in,
                              void* d_out, int out_size, void* d_ws, size_t ws_size,
                              hipStream_t stream)
{
    const float* h   = (const float*)d_in[0];
    const int*   adj = (const int*)d_in[1];
    const float* ef  = (const float*)d_in[2];
    const float* W   = (const float*)d_in[3];
    const float* a   = (const float*)d_in[4];
    float* out = (float*)d_out;

    char* ws = (char*)d_ws;
    unsigned short* wht = (unsigned short*)ws;                       // 1 MB
    float* s1   = (float*)(ws + (size_t)F_OUT * N_NODES * 2);        // 32 KB
    float* s2   = s1 + N_NODES;                                      // 32 KB
    float* Osum = s2 + N_NODES;                                      // 2 MB
    float* lsum = Osum + (size_t)N_NODES * F_OUT;                    // 32 KB

    hipMemsetAsync(Osum, 0, ((size_t)N_NODES * F_OUT + N_NODES) * sizeof(float), stream);

    k_wh  <<<N_NODES / 4, 256, 0, stream>>>(h, W, a, wht, s1, s2);
    k_attn<<<(N_NODES / 64) * JSPLIT, 256, 0, stream>>>(adj, ef, a, s1, s2, wht, Osum, lsum);
    k_out <<<(N_NODES * F_OUT) / 256, 256, 0, stream>>>(Osum, lsum, out);
}